// Round 1
// 256.975 us; speedup vs baseline: 1.0466x; 1.0466x over previous
//
#include <hip/hip_runtime.h>
#include <math.h>

#define LSEQ   4096
#define DMODEL 1024
#define NH     16
#define DHEAD  64
#define PSTRIDE 40  // P-buffer row stride in bf16: mult of 8 (b128 align)
// Finite mask: exp2(-30000) == 0 exactly; below-diagonal tiles contribute
// p=0, l=0, O=0 -> trivially correct under the sum-merge (no NaN path).
#define MASKV  -30000.0f
#define C2SCALE 0.18033688f  // 0.125 * log2(e), folded into Q projection

typedef __attribute__((ext_vector_type(8))) short  bf16x8;
typedef __attribute__((ext_vector_type(4))) float  floatx4;
typedef unsigned short ushort_t;

#if __has_builtin(__builtin_amdgcn_exp2f)
#define EXP2F __builtin_amdgcn_exp2f
#else
#define EXP2F exp2f
#endif

__device__ __forceinline__ ushort_t f2bf(float x) {
  unsigned u = __builtin_bit_cast(unsigned, x);
  return (ushort_t)((u + 0x7fff + ((u >> 16) & 1)) >> 16);
}
__device__ __forceinline__ unsigned bf16pair(float a, float b) {
  return (unsigned)f2bf(a) | ((unsigned)f2bf(b) << 16);
}
// truncating pack: low16 = hi16(a), high16 = hi16(b) — 1 VALU (v_perm_b32)
__device__ __forceinline__ unsigned bfpack_trunc(float a, float b) {
  return __builtin_amdgcn_perm(__builtin_bit_cast(unsigned, b),
                               __builtin_bit_cast(unsigned, a), 0x07060302u);
}
__device__ __forceinline__ void gl_lds16(const ushort_t* g, ushort_t* l) {
  __builtin_amdgcn_global_load_lds(
      (const __attribute__((address_space(1))) void*)g,
      (__attribute__((address_space(3))) void*)l, 16, 0, 0);
}

// ---------------------------------------------------------------------------
// Exact RoPE table: rope[s][t] = {cos(s*invf_t), sin(s*invf_t)}, 4096x32.
// ---------------------------------------------------------------------------
__global__ void rope_table(float2* __restrict__ rope) {
  const int idx = blockIdx.x * 256 + threadIdx.x;  // 131072 total
  const int s = idx >> 5, t = idx & 31;
  const double invf = exp((double)t * -0.28782313662425572);  // -ln(10000)/32
  const double ang = (double)s * invf;
  rope[idx] = make_float2((float)cos(ang), (float)sin(ang));
}

// ---------------------------------------------------------------------------
// fp32 -> bf16 for [x | Wq | Wk | Wv | Wo] into one contiguous buffer.
// ---------------------------------------------------------------------------
__global__ void cvt_bf16(const float* __restrict__ x,  const float* __restrict__ wq,
                         const float* __restrict__ wk, const float* __restrict__ wv,
                         const float* __restrict__ wo, ushort_t* __restrict__ dst) {
  const size_t e = ((size_t)blockIdx.x * 256 + threadIdx.x) * 4;  // elem idx, 8M total
  const float* src; size_t off;
  if      (e < (size_t)(4u << 20)) { src = x;  off = e; }
  else if (e < (size_t)(5u << 20)) { src = wq; off = e - (size_t)(4u << 20); }
  else if (e < (size_t)(6u << 20)) { src = wk; off = e - (size_t)(5u << 20); }
  else if (e < (size_t)(7u << 20)) { src = wv; off = e - (size_t)(6u << 20); }
  else                             { src = wo; off = e - (size_t)(7u << 20); }
  const float4 v = *(const float4*)(src + off);
  uint2 p; p.x = bf16pair(v.x, v.y); p.y = bf16pair(v.z, v.w);
  *(uint2*)(dst + e) = p;
}

// ---------------------------------------------------------------------------
// m97-style bf16 MFMA GEMM (unchanged).
// MODE 0: A=Om(bf16), B=Wo(bf16) -> fp32 C row-major (final projection)
// MODE 1: A=W fused QKV rows (3072xK), B=x. RoPE / V^T epilogues.
//         Q outputs are pre-scaled by C2SCALE (softmax fold).
// ---------------------------------------------------------------------------
template<int MODE>
__global__ __launch_bounds__(256)
void mfma_gemm(const ushort_t* __restrict__ A, const ushort_t* __restrict__ B,
               float* __restrict__ C, const float2* __restrict__ rope,
               ushort_t* __restrict__ Qo, ushort_t* __restrict__ Ko,
               ushort_t* __restrict__ Vo) {
  __shared__ ushort_t As[128 * 64];
  __shared__ ushort_t Bs[128 * 64];
  const int tid  = threadIdx.x;
  const int w    = tid >> 6, lane = tid & 63;
  const int wm   = w >> 1,   wn   = w & 1;
  const int quad = lane >> 4, col = lane & 15;
  const int i0 = blockIdx.x * 128;
  const int j0 = blockIdx.y * 128;

  const ushort_t* Ab = A + (size_t)i0 * DMODEL;
  const ushort_t* Bb = B + (size_t)j0 * DMODEL;

  floatx4 acc[4][4];
#pragma unroll
  for (int mt = 0; mt < 4; ++mt)
#pragma unroll
    for (int nt = 0; nt < 4; ++nt) acc[mt][nt] = (floatx4){0.f, 0.f, 0.f, 0.f};

  const int lrow = lane >> 3;
  const int lcol = (lane & 7) * 8;

  for (int k0 = 0; k0 < DMODEL; k0 += 64) {
    __syncthreads();
#pragma unroll
    for (int it = 0; it < 4; ++it) {
      const int rb = (it * 4 + w) * 8;
      gl_lds16(Ab + (size_t)(rb + lrow) * DMODEL + k0 + lcol, As + rb * 64);
      gl_lds16(Bb + (size_t)(rb + lrow) * DMODEL + k0 + lcol, Bs + rb * 64);
    }
    __syncthreads();

#pragma unroll
    for (int kk = 0; kk < 64; kk += 32) {
      bf16x8 af[4], bfr[4];
#pragma unroll
      for (int mt = 0; mt < 4; ++mt)
        af[mt] = *(const bf16x8*)(As + (wm * 64 + mt * 16 + col) * 64 + kk + quad * 8);
#pragma unroll
      for (int nt = 0; nt < 4; ++nt)
        bfr[nt] = *(const bf16x8*)(Bs + (wn * 64 + nt * 16 + col) * 64 + kk + quad * 8);
#pragma unroll
      for (int mt = 0; mt < 4; ++mt)
#pragma unroll
        for (int nt = 0; nt < 4; ++nt)
          acc[mt][nt] = __builtin_amdgcn_mfma_f32_16x16x32_bf16(
              af[mt], bfr[nt], acc[mt][nt], 0, 0, 0);
    }
  }

  if (MODE == 0) {
#pragma unroll
    for (int mt = 0; mt < 4; ++mt) {
      const int i = i0 + wm * 64 + mt * 16 + quad * 4;
#pragma unroll
      for (int nt = 0; nt < 4; ++nt) {
        const int j = j0 + wn * 64 + nt * 16 + col;
#pragma unroll
        for (int r = 0; r < 4; ++r)
          C[(size_t)(i + r) * DMODEL + j] = acc[mt][nt][r];
      }
    }
  } else {
    const int which = i0 >> 10;               // 0=Q 1=K 2=V
#pragma unroll
    for (int mt = 0; mt < 4; ++mt) {
      const int f0 = i0 + wm * 64 + mt * 16 + quad * 4;
      const int h  = (f0 >> 6) & 15;
      const int d  = f0 & 63;
      if (which == 2) {
#pragma unroll
        for (int nt = 0; nt < 4; ++nt) {
          const int s = j0 + wn * 64 + nt * 16 + col;
#pragma unroll
          for (int r = 0; r < 4; ++r)
            Vo[(size_t)(h * DHEAD + d + r) * LSEQ + s] = f2bf(acc[mt][nt][r]);
        }
      } else {
        ushort_t* dst = which ? Ko : Qo;
        const float qs = which ? 1.0f : C2SCALE;  // fold softmax scale into Q
        const int t0 = d >> 1;
#pragma unroll
        for (int nt = 0; nt < 4; ++nt) {
          const int s = j0 + wn * 64 + nt * 16 + col;
          const float4 cst = *(const float4*)((const float*)rope + ((size_t)s << 6) + t0 * 2);
          ushort_t* ob = dst + ((size_t)h * LSEQ + s) * DHEAD;
          const float x1 = acc[mt][nt][0], x2 = acc[mt][nt][1];
          const float y1 = acc[mt][nt][2], y2 = acc[mt][nt][3];
          *(unsigned*)(ob + t0)      = bf16pair((x1 * cst.x - x2 * cst.y) * qs,
                                                (y1 * cst.z - y2 * cst.w) * qs);
          *(unsigned*)(ob + t0 + 32) = bf16pair((x1 * cst.y + x2 * cst.x) * qs,
                                                (y1 * cst.w + y2 * cst.z) * qs);
        }
      }
    }
  }
}

// ---------------------------------------------------------------------------
// MFMA flash attention v11 = v10 + kt-parity wave-group split.
// R12 counters: OccupancyPercent 19% (grid 256 blocks x 8 waves = 1 block/CU
// = 2 waves/SIMD), MfmaUtil 17.7, VALUBusy 25.5 -> latency-bound, grid-starved.
// Fix: 1024-thread blocks, 16 waves = 4 q-units x 2 key-halves x 2 KT-PARITY
// groups. Group ktpar processes tiles kt = 2*ktt+ktpar with its own LDS
// double-buffer (4 tile buffers total). nkt = 2*qb+2 is always even -> both
// groups perfectly balanced, identical barrier counts, half the barriers per
// wave. Per-wave inner code identical to v10 (incl. XOR bank swizzle).
// Epilogue merges 4 partials (3 dumps + merger) instead of 2.
// LDS: Ks 4x8KB | Vs 4x8KB | P 16x2560B = 104KB + lbuf; Obuf (3x34816B)
// aliases staging after the key loop. 1 block/CU x 16 waves = 2x occupancy.
// ---------------------------------------------------------------------------
__global__ __launch_bounds__(1024, 4)
void attn_mfma(const ushort_t* __restrict__ Qh, const ushort_t* __restrict__ Kh,
               const ushort_t* __restrict__ Vt, ushort_t* __restrict__ Om) {
  const int h   = blockIdx.x;
  const int g   = blockIdx.y;    // 0..15
  const int tid = threadIdx.x;
  const int w     = tid >> 6;      // 0..15
  const int wl    = w & 3;         // q-unit slot (32 q rows each)
  const int half  = (w >> 2) & 1;  // keys [0,32) or [32,64) of each tile
  const int ktpar = w >> 3;        // 0 = even tiles, 1 = odd tiles
  const int wg    = w & 7;         // staging wave index within parity group
  const int lane = tid & 63;
  const int quad = lane >> 4;
  const int col  = lane & 15;
  const int csw  = col & 7;      // row-derived swizzle key for reads

  // LDS map (bytes): Ks 4-buf [0,32768) | Vs 4-buf [32768,65536) |
  //                  P per-wave [65536,106496). Obuf (merge, 3x34816 B)
  //                  aliases the staging region after the key loop.
  __shared__ __align__(16) char smem[106496];
  ushort_t* Ks   = (ushort_t*)smem;                  // [4][64*64], swizzled
  ushort_t* Vs   = (ushort_t*)(smem + 32768);        // [4][64*64], swizzled
  ushort_t* Ps   = (ushort_t*)(smem + 65536);        // [16][32*PSTRIDE]
  float*    Obuf = (float*)smem;
  __shared__ float lbuf[3][4][2][16];
  ushort_t* psw = Ps + w * (32 * PSTRIDE);

  // staging lane geometry: within its parity group, wave wg stages rows
  // [wg*8, wg*8+8); lane's LDS slot is (r = lane>>3, cblk = lane&7); it
  // LOADS global column block cblk ^ (r&7) -> LDS holds tile[r][cb^(r&7)]
  // at slot (r,cb).
  const int srow = wg * 8 + (lane >> 3);
  const int scol = (((lane & 7) ^ ((lane >> 3) & 7)) * 8);

  for (int pass = 0; pass < 2; ++pass) {
    const int qb      = pass ? (31 - g) : g;
    const int qbase   = qb * 128 + wl * 32;
    const int nkt_max = 2 * qb + 2;   // uniform across all waves, always even
    const int nt2     = nkt_max >> 1; // tiles per parity group

    // Q B-frags (pre-scaled by C2), resident for the key loop
    bf16x8 qf[2][2];
#pragma unroll
    for (int nq = 0; nq < 2; ++nq)
#pragma unroll
      for (int c = 0; c < 2; ++c)
        qf[nq][c] = *(const bf16x8*)(Qh +
            ((size_t)(h * LSEQ + qbase + nq * 16 + col)) * DHEAD + quad * 8 + c * 32);

    floatx4 ot[4][2];
#pragma unroll
    for (int md = 0; md < 4; ++md)
#pragma unroll
      for (int nq = 0; nq < 2; ++nq) ot[md][nq] = (floatx4){0.f, 0.f, 0.f, 0.f};
    float l_[2] = {0.f, 0.f};

    // stage tile kt into this parity group's LDS buffer b (0/1)
    auto stage = [&](int kt, int b) {
      const int key0 = kt * 64;
      const int boff = (ktpar * 2 + b) * 4096;
      gl_lds16(Kh + ((size_t)(h * LSEQ + key0 + srow)) * DHEAD + scol,
               Ks + boff + wg * 512);
      gl_lds16(Vt + ((size_t)(h * DHEAD + srow)) * LSEQ + key0 + scol,
               Vs + boff + wg * 512);
    };

    stage(ktpar, 0);   // group 0 stages tile 0, group 1 stages tile 1
    __syncthreads();   // staging visible (barrier drains vmcnt)

    for (int ktt = 0; ktt < nt2; ++ktt) {
      const int kt  = 2 * ktt + ktpar;
      const int buf = ktt & 1;
      if (ktt + 1 < nt2) stage(kt + 2, buf ^ 1);  // fills group's other buffer

      const ushort_t* kb = Ks + (ktpar * 2 + buf) * 4096;
      const ushort_t* vb = Vs + (ktpar * 2 + buf) * 4096;

      // kf frags from LDS (swizzled): row rk = half*32+mk*16+col, rk&7 = csw
      bf16x8 kf[2][2];
#pragma unroll
      for (int mk = 0; mk < 2; ++mk)
#pragma unroll
        for (int c = 0; c < 2; ++c)
          kf[mk][c] = *(const bf16x8*)(kb + (half * 32 + mk * 16 + col) * 64 +
                                       (((c * 4 + quad) ^ csw) * 8));

      // S^T = K . (C2*Q)^T  (32 keys x 32 q)
      floatx4 st[2][2];
#pragma unroll
      for (int mk = 0; mk < 2; ++mk)
#pragma unroll
        for (int nq = 0; nq < 2; ++nq) st[mk][nq] = (floatx4){0.f, 0.f, 0.f, 0.f};
#pragma unroll
      for (int mk = 0; mk < 2; ++mk)
#pragma unroll
        for (int c = 0; c < 2; ++c)
#pragma unroll
          for (int nq = 0; nq < 2; ++nq)
            st[mk][nq] = __builtin_amdgcn_mfma_f32_16x16x32_bf16(
                kf[mk][c], qf[nq][c], st[mk][nq], 0, 0, 0);

      // mask near/beyond the diagonal (absolute indices; below-diag = no-op,
      // beyond-diag tiles mask everything -> p=0)
      if (kt >= nkt_max - 2) {
        const int key0 = kt * 64 + half * 32;
#pragma unroll
        for (int mk = 0; mk < 2; ++mk) {
          const int keyb = key0 + mk * 16 + quad * 4;
#pragma unroll
          for (int nq = 0; nq < 2; ++nq) {
            const int q = qbase + nq * 16 + col;
#pragma unroll
            for (int r = 0; r < 4; ++r)
              if (keyb + r > q) st[mk][nq][r] = MASKV;
          }
        }
      }

      // p = exp2(S); accumulate l per-lane
#pragma unroll
      for (int mk = 0; mk < 2; ++mk)
#pragma unroll
        for (int nq = 0; nq < 2; ++nq) {
#pragma unroll
          for (int r = 0; r < 4; ++r) st[mk][nq][r] = EXP2F(st[mk][nq][r]);
          l_[nq] += (st[mk][nq][0] + st[mk][nq][1]) + (st[mk][nq][2] + st[mk][nq][3]);
        }

      // P^T -> per-wave LDS (truncating pack), then P B-frags
#pragma unroll
      for (int mk = 0; mk < 2; ++mk)
#pragma unroll
        for (int nq = 0; nq < 2; ++nq) {
          uint2 pk;
          pk.x = bfpack_trunc(st[mk][nq][0], st[mk][nq][1]);
          pk.y = bfpack_trunc(st[mk][nq][2], st[mk][nq][3]);
          *(uint2*)(psw + (nq * 16 + col) * PSTRIDE + mk * 16 + quad * 4) = pk;
        }
      bf16x8 pf[2];
#pragma unroll
      for (int nq = 0; nq < 2; ++nq)
        pf[nq] = *(const bf16x8*)(psw + (nq * 16 + col) * PSTRIDE + quad * 8);

      // vf frags from LDS (swizzled): row rv = md*16+col, rv&7 = csw
      bf16x8 vf[4];
#pragma unroll
      for (int md = 0; md < 4; ++md)
        vf[md] = *(const bf16x8*)(vb + (md * 16 + col) * 64 +
                                  (((half * 4 + quad) ^ csw) * 8));
#pragma unroll
      for (int md = 0; md < 4; ++md)
#pragma unroll
        for (int nq = 0; nq < 2; ++nq)
          ot[md][nq] = __builtin_amdgcn_mfma_f32_16x16x32_bf16(
              vf[md], pf[nq], ot[md][nq], 0, 0, 0);

      __syncthreads();  // staging kt+2 done; all reads of this buf finished
    }

    // one-time l reduction per pass
    float lr[2];
#pragma unroll
    for (int nq = 0; nq < 2; ++nq) {
      float ls = l_[nq];
      ls += __shfl_xor(ls, 16);
      ls += __shfl_xor(ls, 32);
      lr[nq] = ls;
    }

    // 3 non-merger groups dump partials (Obuf aliases staging); merger is
    // group (half=0, ktpar=0).
    const int di = ((half << 1) | ktpar) - 1;  // -1 merger, else 0..2
    if (di >= 0) {
#pragma unroll
      for (int nq = 0; nq < 2; ++nq) {
        if (quad == 0) lbuf[di][wl][nq][col] = lr[nq];
#pragma unroll
        for (int md = 0; md < 4; ++md)
          *(float4*)(Obuf + di * 8704 + ((wl * 2 + nq) * 16 + col) * 68 + md * 16 + quad * 4) =
              (float4){ot[md][nq][0], ot[md][nq][1], ot[md][nq][2], ot[md][nq][3]};
      }
    }
    __syncthreads();

    if (di < 0) {  // merger group sums 4 partials and writes Om
#pragma unroll
      for (int nq = 0; nq < 2; ++nq) {
        const float inv = 1.0f / (lr[nq] + lbuf[0][wl][nq][col] +
                                  lbuf[1][wl][nq][col] + lbuf[2][wl][nq][col]);
        const int q = qbase + nq * 16 + col;
#pragma unroll
        for (int md = 0; md < 4; ++md) {
          const int ob_off = ((wl * 2 + nq) * 16 + col) * 68 + md * 16 + quad * 4;
          const float4 o0 = *(const float4*)(Obuf + ob_off);
          const float4 o1 = *(const float4*)(Obuf + 8704 + ob_off);
          const float4 o2 = *(const float4*)(Obuf + 17408 + ob_off);
          uint2 pk;
          pk.x = bf16pair((ot[md][nq][0] + o0.x + o1.x + o2.x) * inv,
                          (ot[md][nq][1] + o0.y + o1.y + o2.y) * inv);
          pk.y = bf16pair((ot[md][nq][2] + o0.z + o1.z + o2.z) * inv,
                          (ot[md][nq][3] + o0.w + o1.w + o2.w) * inv);
          *(uint2*)(Om + (size_t)q * DMODEL + h * DHEAD + md * 16 + quad * 4) = pk;
        }
      }
    }
    __syncthreads();  // Obuf reads done before next pass re-stages over it
  }
}

extern "C" void kernel_launch(void* const* d_in, const int* in_sizes, int n_in,
                              void* d_out, int out_size, void* d_ws, size_t ws_size,
                              hipStream_t stream) {
  const float* x  = (const float*)d_in[0];
  const float* Wq = (const float*)d_in[2];
  const float* Wk = (const float*)d_in[3];
  const float* Wv = (const float*)d_in[4];
  const float* Wo = (const float*)d_in[5];
  float* out = (float*)d_out;

  const size_t M1 = (size_t)1 << 20;
  ushort_t* xb  = (ushort_t*)d_ws;      // bf16 x          4M elems
  ushort_t* Wb  = xb  + 4 * M1;         // bf16 Wq|Wk|Wv   3M (contiguous)
  ushort_t* wob = Wb  + 3 * M1;         // bf16 Wo         1M
  ushort_t* Qh  = wob + 1 * M1;         // bf16 [H][L][DH] 4M (pre-scaled C2)
  ushort_t* Kh  = Qh  + 4 * M1;         // bf16 [H][L][DH] 4M
  ushort_t* Vt  = Kh  + 4 * M1;         // bf16 [H][DH][L] 4M
  ushort_t* Om  = Vt  + 4 * M1;         // bf16 [L][D]     4M
  float2*   rope = (float2*)(Om + 4 * M1);  // 4096x32 float2, 1 MB

  rope_table<<<512, 256, 0, stream>>>(rope);
  cvt_bf16<<<8192, 256, 0, stream>>>(x, Wq, Wk, Wv, Wo, xb);
  mfma_gemm<1><<<dim3(3072 / 128, LSEQ / 128), 256, 0, stream>>>(
      Wb, xb, nullptr, rope, Qh, Kh, Vt);
  attn_mfma<<<dim3(NH, 16), 1024, 0, stream>>>(Qh, Kh, Vt, Om);
  mfma_gemm<0><<<dim3(LSEQ / 128, DMODEL / 128), 256, 0, stream>>>(
      Om, wob, out, nullptr, nullptr, nullptr, nullptr);
}

// Round 2
// 246.479 us; speedup vs baseline: 1.0912x; 1.0426x over previous
//
#include <hip/hip_runtime.h>
#include <math.h>

#define LSEQ   4096
#define DMODEL 1024
#define NH     16
#define DHEAD  64
#define PSTRIDE 40  // P-buffer row stride in bf16: mult of 8 (b128 align)
// Finite mask: exp2(-30000) == 0 exactly; below-diagonal tiles contribute
// p=0, l=0, O=0 -> trivially correct under the sum-merge (no NaN path).
#define MASKV  -30000.0f
#define C2SCALE 0.18033688f  // 0.125 * log2(e), folded into Q projection

typedef __attribute__((ext_vector_type(8))) short  bf16x8;
typedef __attribute__((ext_vector_type(4))) float  floatx4;
typedef unsigned short ushort_t;

#if __has_builtin(__builtin_amdgcn_exp2f)
#define EXP2F __builtin_amdgcn_exp2f
#else
#define EXP2F exp2f
#endif

__device__ __forceinline__ ushort_t f2bf(float x) {
  unsigned u = __builtin_bit_cast(unsigned, x);
  return (ushort_t)((u + 0x7fff + ((u >> 16) & 1)) >> 16);
}
__device__ __forceinline__ unsigned bf16pair(float a, float b) {
  return (unsigned)f2bf(a) | ((unsigned)f2bf(b) << 16);
}
// truncating pack: low16 = hi16(a), high16 = hi16(b) — 1 VALU (v_perm_b32)
__device__ __forceinline__ unsigned bfpack_trunc(float a, float b) {
  return __builtin_amdgcn_perm(__builtin_bit_cast(unsigned, b),
                               __builtin_bit_cast(unsigned, a), 0x07060302u);
}
__device__ __forceinline__ void gl_lds16(const ushort_t* g, ushort_t* l) {
  __builtin_amdgcn_global_load_lds(
      (const __attribute__((address_space(1))) void*)g,
      (__attribute__((address_space(3))) void*)l, 16, 0, 0);
}

// ---------------------------------------------------------------------------
// Exact RoPE table: rope[s][t] = {cos(s*invf_t), sin(s*invf_t)}, 4096x32.
// ---------------------------------------------------------------------------
__global__ void rope_table(float2* __restrict__ rope) {
  const int idx = blockIdx.x * 256 + threadIdx.x;  // 131072 total
  const int s = idx >> 5, t = idx & 31;
  const double invf = exp((double)t * -0.28782313662425572);  // -ln(10000)/32
  const double ang = (double)s * invf;
  rope[idx] = make_float2((float)cos(ang), (float)sin(ang));
}

// ---------------------------------------------------------------------------
// fp32 -> bf16 for [x | Wq | Wk | Wv | Wo] into one contiguous buffer.
// ---------------------------------------------------------------------------
__global__ void cvt_bf16(const float* __restrict__ x,  const float* __restrict__ wq,
                         const float* __restrict__ wk, const float* __restrict__ wv,
                         const float* __restrict__ wo, ushort_t* __restrict__ dst) {
  const size_t e = ((size_t)blockIdx.x * 256 + threadIdx.x) * 4;  // elem idx, 8M total
  const float* src; size_t off;
  if      (e < (size_t)(4u << 20)) { src = x;  off = e; }
  else if (e < (size_t)(5u << 20)) { src = wq; off = e - (size_t)(4u << 20); }
  else if (e < (size_t)(6u << 20)) { src = wk; off = e - (size_t)(5u << 20); }
  else if (e < (size_t)(7u << 20)) { src = wv; off = e - (size_t)(6u << 20); }
  else                             { src = wo; off = e - (size_t)(7u << 20); }
  const float4 v = *(const float4*)(src + off);
  uint2 p; p.x = bf16pair(v.x, v.y); p.y = bf16pair(v.z, v.w);
  *(uint2*)(dst + e) = p;
}

// ---------------------------------------------------------------------------
// m97-style bf16 MFMA GEMM + XOR-swizzled LDS (new this round).
// R13 counters: SQ_LDS_BANK_CONFLICT 9.4M cy on MODE1 (75 us, MfmaUtil 13%).
// [128][64] bf16 tiles have 128 B rows -> every af/bfr ds_read_b128 hits one
// 4-bank slot across all 16 col-lanes (16-way conflict, ~5.7x, m136); the
// LDS pipe serializes 4 waves x 16 reads/step and dominates the kernel.
// Fix = same both-sides swizzle as attn: LDS dest stays linear (gl_lds16
// requirement), per-lane GLOBAL source column-block is cb^(r&7), and reads
// XOR the same key (folds into addr calc, zero extra instructions). Lanes
// then spread across 8 distinct 16B slots -> 2-way (free).
// MODE 0: A=Om(bf16), B=Wo(bf16) -> fp32 C row-major (final projection)
// MODE 1: A=W fused QKV rows (3072xK), B=x. RoPE / V^T epilogues.
//         Q outputs are pre-scaled by C2SCALE (softmax fold).
// ---------------------------------------------------------------------------
template<int MODE>
__global__ __launch_bounds__(256)
void mfma_gemm(const ushort_t* __restrict__ A, const ushort_t* __restrict__ B,
               float* __restrict__ C, const float2* __restrict__ rope,
               ushort_t* __restrict__ Qo, ushort_t* __restrict__ Ko,
               ushort_t* __restrict__ Vo) {
  __shared__ ushort_t As[128 * 64];
  __shared__ ushort_t Bs[128 * 64];
  const int tid  = threadIdx.x;
  const int w    = tid >> 6, lane = tid & 63;
  const int wm   = w >> 1,   wn   = w & 1;
  const int quad = lane >> 4, col = lane & 15;
  const int csw  = col & 7;   // row-derived swizzle key: read row % 8 == col % 8
  const int i0 = blockIdx.x * 128;
  const int j0 = blockIdx.y * 128;

  const ushort_t* Ab = A + (size_t)i0 * DMODEL;
  const ushort_t* Bb = B + (size_t)j0 * DMODEL;

  floatx4 acc[4][4];
#pragma unroll
  for (int mt = 0; mt < 4; ++mt)
#pragma unroll
    for (int nt = 0; nt < 4; ++nt) acc[mt][nt] = (floatx4){0.f, 0.f, 0.f, 0.f};

  // staging lane geometry: lane's LDS slot is (r = lane>>3, cblk = lane&7);
  // it LOADS global column block cblk ^ (r&7) -> LDS holds tile[r][cb^(r&7)]
  // at slot (r,cb).
  const int lrow = lane >> 3;
  const int lcol = ((lane & 7) ^ lrow) * 8;

  for (int k0 = 0; k0 < DMODEL; k0 += 64) {
    __syncthreads();
#pragma unroll
    for (int it = 0; it < 4; ++it) {
      const int rb = (it * 4 + w) * 8;
      gl_lds16(Ab + (size_t)(rb + lrow) * DMODEL + k0 + lcol, As + rb * 64);
      gl_lds16(Bb + (size_t)(rb + lrow) * DMODEL + k0 + lcol, Bs + rb * 64);
    }
    __syncthreads();

#pragma unroll
    for (int kk = 0; kk < 64; kk += 32) {
      // logical col-block (kk>>3)+quad of row; stored at slot ^ (row&7)=csw
      const int cblk = (kk >> 3) + quad;
      bf16x8 af[4], bfr[4];
#pragma unroll
      for (int mt = 0; mt < 4; ++mt)
        af[mt] = *(const bf16x8*)(As + (wm * 64 + mt * 16 + col) * 64 +
                                  ((cblk ^ csw) * 8));
#pragma unroll
      for (int nt = 0; nt < 4; ++nt)
        bfr[nt] = *(const bf16x8*)(Bs + (wn * 64 + nt * 16 + col) * 64 +
                                   ((cblk ^ csw) * 8));
#pragma unroll
      for (int mt = 0; mt < 4; ++mt)
#pragma unroll
        for (int nt = 0; nt < 4; ++nt)
          acc[mt][nt] = __builtin_amdgcn_mfma_f32_16x16x32_bf16(
              af[mt], bfr[nt], acc[mt][nt], 0, 0, 0);
    }
  }

  if (MODE == 0) {
#pragma unroll
    for (int mt = 0; mt < 4; ++mt) {
      const int i = i0 + wm * 64 + mt * 16 + quad * 4;
#pragma unroll
      for (int nt = 0; nt < 4; ++nt) {
        const int j = j0 + wn * 64 + nt * 16 + col;
#pragma unroll
        for (int r = 0; r < 4; ++r)
          C[(size_t)(i + r) * DMODEL + j] = acc[mt][nt][r];
      }
    }
  } else {
    const int which = i0 >> 10;               // 0=Q 1=K 2=V
#pragma unroll
    for (int mt = 0; mt < 4; ++mt) {
      const int f0 = i0 + wm * 64 + mt * 16 + quad * 4;
      const int h  = (f0 >> 6) & 15;
      const int d  = f0 & 63;
      if (which == 2) {
#pragma unroll
        for (int nt = 0; nt < 4; ++nt) {
          const int s = j0 + wn * 64 + nt * 16 + col;
#pragma unroll
          for (int r = 0; r < 4; ++r)
            Vo[(size_t)(h * DHEAD + d + r) * LSEQ + s] = f2bf(acc[mt][nt][r]);
        }
      } else {
        ushort_t* dst = which ? Ko : Qo;
        const float qs = which ? 1.0f : C2SCALE;  // fold softmax scale into Q
        const int t0 = d >> 1;
#pragma unroll
        for (int nt = 0; nt < 4; ++nt) {
          const int s = j0 + wn * 64 + nt * 16 + col;
          const float4 cst = *(const float4*)((const float*)rope + ((size_t)s << 6) + t0 * 2);
          ushort_t* ob = dst + ((size_t)h * LSEQ + s) * DHEAD;
          const float x1 = acc[mt][nt][0], x2 = acc[mt][nt][1];
          const float y1 = acc[mt][nt][2], y2 = acc[mt][nt][3];
          *(unsigned*)(ob + t0)      = bf16pair((x1 * cst.x - x2 * cst.y) * qs,
                                                (y1 * cst.z - y2 * cst.w) * qs);
          *(unsigned*)(ob + t0 + 32) = bf16pair((x1 * cst.y + x2 * cst.x) * qs,
                                                (y1 * cst.w + y2 * cst.z) * qs);
        }
      }
    }
  }
}

// ---------------------------------------------------------------------------
// MFMA flash attention v11 = v10 + kt-parity wave-group split (unchanged).
// 1024-thread blocks, 16 waves = 4 q-units x 2 key-halves x 2 KT-PARITY
// groups. Group ktpar processes tiles kt = 2*ktt+ktpar with its own LDS
// double-buffer (4 tile buffers total). nkt = 2*qb+2 is always even -> both
// groups perfectly balanced, identical barrier counts, half the barriers per
// wave. Epilogue merges 4 partials (3 dumps + merger).
// LDS: Ks 4x8KB | Vs 4x8KB | P 16x2560B = 104KB + lbuf; Obuf (3x34816B)
// aliases staging after the key loop. 1 block/CU x 16 waves.
// ---------------------------------------------------------------------------
__global__ __launch_bounds__(1024, 4)
void attn_mfma(const ushort_t* __restrict__ Qh, const ushort_t* __restrict__ Kh,
               const ushort_t* __restrict__ Vt, ushort_t* __restrict__ Om) {
  const int h   = blockIdx.x;
  const int g   = blockIdx.y;    // 0..15
  const int tid = threadIdx.x;
  const int w     = tid >> 6;      // 0..15
  const int wl    = w & 3;         // q-unit slot (32 q rows each)
  const int half  = (w >> 2) & 1;  // keys [0,32) or [32,64) of each tile
  const int ktpar = w >> 3;        // 0 = even tiles, 1 = odd tiles
  const int wg    = w & 7;         // staging wave index within parity group
  const int lane = tid & 63;
  const int quad = lane >> 4;
  const int col  = lane & 15;
  const int csw  = col & 7;      // row-derived swizzle key for reads

  // LDS map (bytes): Ks 4-buf [0,32768) | Vs 4-buf [32768,65536) |
  //                  P per-wave [65536,106496). Obuf (merge, 3x34816 B)
  //                  aliases the staging region after the key loop.
  __shared__ __align__(16) char smem[106496];
  ushort_t* Ks   = (ushort_t*)smem;                  // [4][64*64], swizzled
  ushort_t* Vs   = (ushort_t*)(smem + 32768);        // [4][64*64], swizzled
  ushort_t* Ps   = (ushort_t*)(smem + 65536);        // [16][32*PSTRIDE]
  float*    Obuf = (float*)smem;
  __shared__ float lbuf[3][4][2][16];
  ushort_t* psw = Ps + w * (32 * PSTRIDE);

  // staging lane geometry: within its parity group, wave wg stages rows
  // [wg*8, wg*8+8); lane's LDS slot is (r = lane>>3, cblk = lane&7); it
  // LOADS global column block cblk ^ (r&7) -> LDS holds tile[r][cb^(r&7)]
  // at slot (r,cb).
  const int srow = wg * 8 + (lane >> 3);
  const int scol = (((lane & 7) ^ ((lane >> 3) & 7)) * 8);

  for (int pass = 0; pass < 2; ++pass) {
    const int qb      = pass ? (31 - g) : g;
    const int qbase   = qb * 128 + wl * 32;
    const int nkt_max = 2 * qb + 2;   // uniform across all waves, always even
    const int nt2     = nkt_max >> 1; // tiles per parity group

    // Q B-frags (pre-scaled by C2), resident for the key loop
    bf16x8 qf[2][2];
#pragma unroll
    for (int nq = 0; nq < 2; ++nq)
#pragma unroll
      for (int c = 0; c < 2; ++c)
        qf[nq][c] = *(const bf16x8*)(Qh +
            ((size_t)(h * LSEQ + qbase + nq * 16 + col)) * DHEAD + quad * 8 + c * 32);

    floatx4 ot[4][2];
#pragma unroll
    for (int md = 0; md < 4; ++md)
#pragma unroll
      for (int nq = 0; nq < 2; ++nq) ot[md][nq] = (floatx4){0.f, 0.f, 0.f, 0.f};
    float l_[2] = {0.f, 0.f};

    // stage tile kt into this parity group's LDS buffer b (0/1)
    auto stage = [&](int kt, int b) {
      const int key0 = kt * 64;
      const int boff = (ktpar * 2 + b) * 4096;
      gl_lds16(Kh + ((size_t)(h * LSEQ + key0 + srow)) * DHEAD + scol,
               Ks + boff + wg * 512);
      gl_lds16(Vt + ((size_t)(h * DHEAD + srow)) * LSEQ + key0 + scol,
               Vs + boff + wg * 512);
    };

    stage(ktpar, 0);   // group 0 stages tile 0, group 1 stages tile 1
    __syncthreads();   // staging visible (barrier drains vmcnt)

    for (int ktt = 0; ktt < nt2; ++ktt) {
      const int kt  = 2 * ktt + ktpar;
      const int buf = ktt & 1;
      if (ktt + 1 < nt2) stage(kt + 2, buf ^ 1);  // fills group's other buffer

      const ushort_t* kb = Ks + (ktpar * 2 + buf) * 4096;
      const ushort_t* vb = Vs + (ktpar * 2 + buf) * 4096;

      // kf frags from LDS (swizzled): row rk = half*32+mk*16+col, rk&7 = csw
      bf16x8 kf[2][2];
#pragma unroll
      for (int mk = 0; mk < 2; ++mk)
#pragma unroll
        for (int c = 0; c < 2; ++c)
          kf[mk][c] = *(const bf16x8*)(kb + (half * 32 + mk * 16 + col) * 64 +
                                       (((c * 4 + quad) ^ csw) * 8));

      // S^T = K . (C2*Q)^T  (32 keys x 32 q)
      floatx4 st[2][2];
#pragma unroll
      for (int mk = 0; mk < 2; ++mk)
#pragma unroll
        for (int nq = 0; nq < 2; ++nq) st[mk][nq] = (floatx4){0.f, 0.f, 0.f, 0.f};
#pragma unroll
      for (int mk = 0; mk < 2; ++mk)
#pragma unroll
        for (int c = 0; c < 2; ++c)
#pragma unroll
          for (int nq = 0; nq < 2; ++nq)
            st[mk][nq] = __builtin_amdgcn_mfma_f32_16x16x32_bf16(
                kf[mk][c], qf[nq][c], st[mk][nq], 0, 0, 0);

      // mask near/beyond the diagonal (absolute indices; below-diag = no-op,
      // beyond-diag tiles mask everything -> p=0)
      if (kt >= nkt_max - 2) {
        const int key0 = kt * 64 + half * 32;
#pragma unroll
        for (int mk = 0; mk < 2; ++mk) {
          const int keyb = key0 + mk * 16 + quad * 4;
#pragma unroll
          for (int nq = 0; nq < 2; ++nq) {
            const int q = qbase + nq * 16 + col;
#pragma unroll
            for (int r = 0; r < 4; ++r)
              if (keyb + r > q) st[mk][nq][r] = MASKV;
          }
        }
      }

      // p = exp2(S); accumulate l per-lane
#pragma unroll
      for (int mk = 0; mk < 2; ++mk)
#pragma unroll
        for (int nq = 0; nq < 2; ++nq) {
#pragma unroll
          for (int r = 0; r < 4; ++r) st[mk][nq][r] = EXP2F(st[mk][nq][r]);
          l_[nq] += (st[mk][nq][0] + st[mk][nq][1]) + (st[mk][nq][2] + st[mk][nq][3]);
        }

      // P^T -> per-wave LDS (truncating pack), then P B-frags
#pragma unroll
      for (int mk = 0; mk < 2; ++mk)
#pragma unroll
        for (int nq = 0; nq < 2; ++nq) {
          uint2 pk;
          pk.x = bfpack_trunc(st[mk][nq][0], st[mk][nq][1]);
          pk.y = bfpack_trunc(st[mk][nq][2], st[mk][nq][3]);
          *(uint2*)(psw + (nq * 16 + col) * PSTRIDE + mk * 16 + quad * 4) = pk;
        }
      bf16x8 pf[2];
#pragma unroll
      for (int nq = 0; nq < 2; ++nq)
        pf[nq] = *(const bf16x8*)(psw + (nq * 16 + col) * PSTRIDE + quad * 8);

      // vf frags from LDS (swizzled): row rv = md*16+col, rv&7 = csw
      bf16x8 vf[4];
#pragma unroll
      for (int md = 0; md < 4; ++md)
        vf[md] = *(const bf16x8*)(vb + (md * 16 + col) * 64 +
                                  (((half * 4 + quad) ^ csw) * 8));
#pragma unroll
      for (int md = 0; md < 4; ++md)
#pragma unroll
        for (int nq = 0; nq < 2; ++nq)
          ot[md][nq] = __builtin_amdgcn_mfma_f32_16x16x32_bf16(
              vf[md], pf[nq], ot[md][nq], 0, 0, 0);

      __syncthreads();  // staging kt+2 done; all reads of this buf finished
    }

    // one-time l reduction per pass
    float lr[2];
#pragma unroll
    for (int nq = 0; nq < 2; ++nq) {
      float ls = l_[nq];
      ls += __shfl_xor(ls, 16);
      ls += __shfl_xor(ls, 32);
      lr[nq] = ls;
    }

    // 3 non-merger groups dump partials (Obuf aliases staging); merger is
    // group (half=0, ktpar=0).
    const int di = ((half << 1) | ktpar) - 1;  // -1 merger, else 0..2
    if (di >= 0) {
#pragma unroll
      for (int nq = 0; nq < 2; ++nq) {
        if (quad == 0) lbuf[di][wl][nq][col] = lr[nq];
#pragma unroll
        for (int md = 0; md < 4; ++md)
          *(float4*)(Obuf + di * 8704 + ((wl * 2 + nq) * 16 + col) * 68 + md * 16 + quad * 4) =
              (float4){ot[md][nq][0], ot[md][nq][1], ot[md][nq][2], ot[md][nq][3]};
      }
    }
    __syncthreads();

    if (di < 0) {  // merger group sums 4 partials and writes Om
#pragma unroll
      for (int nq = 0; nq < 2; ++nq) {
        const float inv = 1.0f / (lr[nq] + lbuf[0][wl][nq][col] +
                                  lbuf[1][wl][nq][col] + lbuf[2][wl][nq][col]);
        const int q = qbase + nq * 16 + col;
#pragma unroll
        for (int md = 0; md < 4; ++md) {
          const int ob_off = ((wl * 2 + nq) * 16 + col) * 68 + md * 16 + quad * 4;
          const float4 o0 = *(const float4*)(Obuf + ob_off);
          const float4 o1 = *(const float4*)(Obuf + 8704 + ob_off);
          const float4 o2 = *(const float4*)(Obuf + 17408 + ob_off);
          uint2 pk;
          pk.x = bf16pair((ot[md][nq][0] + o0.x + o1.x + o2.x) * inv,
                          (ot[md][nq][1] + o0.y + o1.y + o2.y) * inv);
          pk.y = bf16pair((ot[md][nq][2] + o0.z + o1.z + o2.z) * inv,
                          (ot[md][nq][3] + o0.w + o1.w + o2.w) * inv);
          *(uint2*)(Om + (size_t)q * DMODEL + h * DHEAD + md * 16 + quad * 4) = pk;
        }
      }
    }
    __syncthreads();  // Obuf reads done before next pass re-stages over it
  }
}

extern "C" void kernel_launch(void* const* d_in, const int* in_sizes, int n_in,
                              void* d_out, int out_size, void* d_ws, size_t ws_size,
                              hipStream_t stream) {
  const float* x  = (const float*)d_in[0];
  const float* Wq = (const float*)d_in[2];
  const float* Wk = (const float*)d_in[3];
  const float* Wv = (const float*)d_in[4];
  const float* Wo = (const float*)d_in[5];
  float* out = (float*)d_out;

  const size_t M1 = (size_t)1 << 20;
  ushort_t* xb  = (ushort_t*)d_ws;      // bf16 x          4M elems
  ushort_t* Wb  = xb  + 4 * M1;         // bf16 Wq|Wk|Wv   3M (contiguous)
  ushort_t* wob = Wb  + 3 * M1;         // bf16 Wo         1M
  ushort_t* Qh  = wob + 1 * M1;         // bf16 [H][L][DH] 4M (pre-scaled C2)
  ushort_t* Kh  = Qh  + 4 * M1;         // bf16 [H][L][DH] 4M
  ushort_t* Vt  = Kh  + 4 * M1;         // bf16 [H][DH][L] 4M
  ushort_t* Om  = Vt  + 4 * M1;         // bf16 [L][D]     4M
  float2*   rope = (float2*)(Om + 4 * M1);  // 4096x32 float2, 1 MB

  rope_table<<<512, 256, 0, stream>>>(rope);
  cvt_bf16<<<8192, 256, 0, stream>>>(x, Wq, Wk, Wv, Wo, xb);
  mfma_gemm<1><<<dim3(3072 / 128, LSEQ / 128), 256, 0, stream>>>(
      Wb, xb, nullptr, rope, Qh, Kh, Vt);
  attn_mfma<<<dim3(NH, 16), 1024, 0, stream>>>(Qh, Kh, Vt, Om);
  mfma_gemm<0><<<dim3(LSEQ / 128, DMODEL / 128), 256, 0, stream>>>(
      Om, wob, out, nullptr, nullptr, nullptr, nullptr);
}

// Round 3
// 239.464 us; speedup vs baseline: 1.1232x; 1.0293x over previous
//
#include <hip/hip_runtime.h>
#include <math.h>

#define LSEQ   4096
#define DMODEL 1024
#define NH     16
#define DHEAD  64
#define PSTRIDE 40  // P-buffer row stride in bf16: mult of 8 (b128 align)
// Finite mask: exp2(-30000) == 0 exactly; below-diagonal tiles contribute
// p=0, l=0, O=0 -> trivially correct under the sum-merge (no NaN path).
#define MASKV  -30000.0f
#define C2SCALE 0.18033688f  // 0.125 * log2(e), folded into Q projection

typedef __attribute__((ext_vector_type(8))) short  bf16x8;
typedef __attribute__((ext_vector_type(4))) float  floatx4;
typedef unsigned short ushort_t;

#if __has_builtin(__builtin_amdgcn_exp2f)
#define EXP2F __builtin_amdgcn_exp2f
#else
#define EXP2F exp2f
#endif

__device__ __forceinline__ ushort_t f2bf(float x) {
  unsigned u = __builtin_bit_cast(unsigned, x);
  return (ushort_t)((u + 0x7fff + ((u >> 16) & 1)) >> 16);
}
__device__ __forceinline__ unsigned bf16pair(float a, float b) {
  return (unsigned)f2bf(a) | ((unsigned)f2bf(b) << 16);
}
// truncating pack: low16 = hi16(a), high16 = hi16(b) — 1 VALU (v_perm_b32)
__device__ __forceinline__ unsigned bfpack_trunc(float a, float b) {
  return __builtin_amdgcn_perm(__builtin_bit_cast(unsigned, b),
                               __builtin_bit_cast(unsigned, a), 0x07060302u);
}
__device__ __forceinline__ void gl_lds16(const ushort_t* g, ushort_t* l) {
  __builtin_amdgcn_global_load_lds(
      (const __attribute__((address_space(1))) void*)g,
      (__attribute__((address_space(3))) void*)l, 16, 0, 0);
}

// ---------------------------------------------------------------------------
// Exact RoPE table: rope[s][t] = {cos(s*invf_t), sin(s*invf_t)}, 4096x32.
// ---------------------------------------------------------------------------
__global__ void rope_table(float2* __restrict__ rope) {
  const int idx = blockIdx.x * 256 + threadIdx.x;  // 131072 total
  const int s = idx >> 5, t = idx & 31;
  const double invf = exp((double)t * -0.28782313662425572);  // -ln(10000)/32
  const double ang = (double)s * invf;
  rope[idx] = make_float2((float)cos(ang), (float)sin(ang));
}

// ---------------------------------------------------------------------------
// fp32 -> bf16 for [x | Wq | Wk | Wv | Wo] into one contiguous buffer.
// ---------------------------------------------------------------------------
__global__ void cvt_bf16(const float* __restrict__ x,  const float* __restrict__ wq,
                         const float* __restrict__ wk, const float* __restrict__ wv,
                         const float* __restrict__ wo, ushort_t* __restrict__ dst) {
  const size_t e = ((size_t)blockIdx.x * 256 + threadIdx.x) * 4;  // elem idx, 8M total
  const float* src; size_t off;
  if      (e < (size_t)(4u << 20)) { src = x;  off = e; }
  else if (e < (size_t)(5u << 20)) { src = wq; off = e - (size_t)(4u << 20); }
  else if (e < (size_t)(6u << 20)) { src = wk; off = e - (size_t)(5u << 20); }
  else if (e < (size_t)(7u << 20)) { src = wv; off = e - (size_t)(6u << 20); }
  else                             { src = wo; off = e - (size_t)(7u << 20); }
  const float4 v = *(const float4*)(src + off);
  uint2 p; p.x = bf16pair(v.x, v.y); p.y = bf16pair(v.z, v.w);
  *(uint2*)(dst + e) = p;
}

// ---------------------------------------------------------------------------
// 256^2-tile 4-phase QKV GEMM (new this round) — replaces mfma_gemm<1>.
// R14: gemm1 stuck at ~450 TF in the 2-barrier m97 structure (MfmaUtil 13%,
// two vmcnt(0) drains per K-step, no in-block load/compute overlap). Port to
// the proven 256^2 multi-phase template (T2+T3+T5, m198/m201: 1167-1563 TF):
//  - 512 thr / 8 waves (2M x 4N); per-wave C = 128x64 = acc[8][4] (128 VGPR)
//  - BK=64; LDS = 2 K-tile dbuf x (A 32KB + B 32KB) = 128 KiB, linear dest
//    + both-sides XOR swizzle (slot cb holds global cb^(row&7); reads XOR
//    (col&7)) -> 2-way bank aliasing (free)
//  - 4 phases per K-tile: {ds_read frags; stage issue (phases 0-1 stage
//    K-tile t+1's half-tiles -> ~3-4 phases of load lead); setprio(1);
//    16 MFMA; setprio(0); s_barrier}
//  - raw s_barrier + ONE asm vmcnt(0) per K-tile boundary (loads stay in
//    flight across the per-phase barriers; the asm also compiler-fences
//    next-tile ds_reads from hoisting above the drain)
// Epilogues identical per-fragment to the old kernel (same C/D layout):
// Q/K get RoPE (Q pre-scaled C2SCALE), V is written transposed [H][DH][L].
// ---------------------------------------------------------------------------
__global__ __launch_bounds__(512, 2)
void gemm256_qkv(const ushort_t* __restrict__ A, const ushort_t* __restrict__ B,
                 const float2* __restrict__ rope,
                 ushort_t* __restrict__ Qo, ushort_t* __restrict__ Ko,
                 ushort_t* __restrict__ Vo) {
  // elem layout: A0 [0,16384) | A1 [16384,32768) | B0 [32768,49152) | B1 [49152,65536)
  __shared__ __align__(16) ushort_t smem[65536];
  const int tid  = threadIdx.x;
  const int w    = tid >> 6, lane = tid & 63;
  const int wr   = w >> 2,   wc   = w & 3;     // wave -> (Mhalf, Nquarter)
  const int quad = lane >> 4, col = lane & 15;
  const int csw  = col & 7;                    // read-side swizzle key
  const int i0 = blockIdx.x * 256;             // feature rows (Q|K|V)
  const int j0 = blockIdx.y * 256;             // sequence cols

  const ushort_t* Ab = A + (size_t)i0 * DMODEL;
  const ushort_t* Bb = B + (size_t)j0 * DMODEL;

  // staging lane geometry: per wave-issue, lane slot (r=lane>>3, cb=lane&7);
  // loads global column block cb ^ (r&7) -> LDS slot (r,cb) holds tile[r][cb^(r&7)]
  const int sr8 = lane >> 3;
  const int sc  = ((lane & 7) ^ sr8) * 8;

  floatx4 acc[8][4];
#pragma unroll
  for (int m = 0; m < 8; ++m)
#pragma unroll
    for (int n = 0; n < 4; ++n) acc[m][n] = (floatx4){0.f, 0.f, 0.f, 0.f};

  // stage half h (128 rows) of A/B K-tile kt into buffer kt&1 (2 gl_lds16 ea)
  auto stageA = [&](int kt, int h) {
    ushort_t* dst = smem + (kt & 1) * 16384 + (h * 128 + w * 8) * 64;
    const ushort_t* src = Ab + (size_t)(h * 128 + w * 8 + sr8) * DMODEL + kt * 64 + sc;
    gl_lds16(src, dst);
    gl_lds16(src + (size_t)64 * DMODEL, dst + 4096);
  };
  auto stageB = [&](int kt, int h) {
    ushort_t* dst = smem + 32768 + (kt & 1) * 16384 + (h * 128 + w * 8) * 64;
    const ushort_t* src = Bb + (size_t)(h * 128 + w * 8 + sr8) * DMODEL + kt * 64 + sc;
    gl_lds16(src, dst);
    gl_lds16(src + (size_t)64 * DMODEL, dst + 4096);
  };

  // prologue: K-tile 0 fully staged, then enter the pipelined loop
  stageA(0, 0); stageB(0, 0); stageA(0, 1); stageB(0, 1);
  asm volatile("s_waitcnt vmcnt(0)" ::: "memory");
  __builtin_amdgcn_s_barrier();

#pragma unroll 2
  for (int t = 0; t < 16; ++t) {
    const ushort_t* As_ = smem + (t & 1) * 16384;
    const ushort_t* Bs_ = smem + 32768 + (t & 1) * 16384;
    const bool pre = (t + 1 < 16);

    bf16x8 af[4], bfr[4];
    // ---- phase 0: kk=0, m-rows 0..3, all n ----
#pragma unroll
    for (int n = 0; n < 4; ++n)
      bfr[n] = *(const bf16x8*)(Bs_ + (wc * 64 + n * 16 + col) * 64 + ((quad ^ csw) * 8));
#pragma unroll
    for (int m = 0; m < 4; ++m)
      af[m] = *(const bf16x8*)(As_ + (wr * 128 + m * 16 + col) * 64 + ((quad ^ csw) * 8));
    if (pre) { stageA(t + 1, 0); stageB(t + 1, 0); }
    __builtin_amdgcn_s_setprio(1);
#pragma unroll
    for (int m = 0; m < 4; ++m)
#pragma unroll
      for (int n = 0; n < 4; ++n)
        acc[m][n] = __builtin_amdgcn_mfma_f32_16x16x32_bf16(af[m], bfr[n], acc[m][n], 0, 0, 0);
    __builtin_amdgcn_s_setprio(0);
    __builtin_amdgcn_s_barrier();

    // ---- phase 1: kk=0, m-rows 4..7 (B-frags reused) ----
#pragma unroll
    for (int m = 0; m < 4; ++m)
      af[m] = *(const bf16x8*)(As_ + (wr * 128 + (m + 4) * 16 + col) * 64 + ((quad ^ csw) * 8));
    if (pre) { stageA(t + 1, 1); stageB(t + 1, 1); }
    __builtin_amdgcn_s_setprio(1);
#pragma unroll
    for (int m = 0; m < 4; ++m)
#pragma unroll
      for (int n = 0; n < 4; ++n)
        acc[m + 4][n] = __builtin_amdgcn_mfma_f32_16x16x32_bf16(af[m], bfr[n], acc[m + 4][n], 0, 0, 0);
    __builtin_amdgcn_s_setprio(0);
    __builtin_amdgcn_s_barrier();

    // ---- phase 2: kk=1, m-rows 0..3 ----
#pragma unroll
    for (int n = 0; n < 4; ++n)
      bfr[n] = *(const bf16x8*)(Bs_ + (wc * 64 + n * 16 + col) * 64 + (((4 + quad) ^ csw) * 8));
#pragma unroll
    for (int m = 0; m < 4; ++m)
      af[m] = *(const bf16x8*)(As_ + (wr * 128 + m * 16 + col) * 64 + (((4 + quad) ^ csw) * 8));
    __builtin_amdgcn_s_setprio(1);
#pragma unroll
    for (int m = 0; m < 4; ++m)
#pragma unroll
      for (int n = 0; n < 4; ++n)
        acc[m][n] = __builtin_amdgcn_mfma_f32_16x16x32_bf16(af[m], bfr[n], acc[m][n], 0, 0, 0);
    __builtin_amdgcn_s_setprio(0);
    __builtin_amdgcn_s_barrier();

    // ---- phase 3: kk=1, m-rows 4..7, then K-tile boundary drain ----
#pragma unroll
    for (int m = 0; m < 4; ++m)
      af[m] = *(const bf16x8*)(As_ + (wr * 128 + (m + 4) * 16 + col) * 64 + (((4 + quad) ^ csw) * 8));
    __builtin_amdgcn_s_setprio(1);
#pragma unroll
    for (int m = 0; m < 4; ++m)
#pragma unroll
      for (int n = 0; n < 4; ++n)
        acc[m + 4][n] = __builtin_amdgcn_mfma_f32_16x16x32_bf16(af[m], bfr[n], acc[m + 4][n], 0, 0, 0);
    __builtin_amdgcn_s_setprio(0);
    // next tile's staging complete; also fences next-phase ds_reads (compiler
    // "memory" barrier) so they can't hoist above the drain.
    asm volatile("s_waitcnt vmcnt(0)" ::: "memory");
    __builtin_amdgcn_s_barrier();
  }

  // ---- epilogue: identical per-fragment mapping to mfma_gemm<1> ----
  const int which = i0 >> 10;               // 0=Q 1=K 2=V (256 | 1024 boundaries)
#pragma unroll
  for (int m = 0; m < 8; ++m) {
    const int f0 = i0 + wr * 128 + m * 16 + quad * 4;
    const int h  = (f0 >> 6) & 15;
    const int d  = f0 & 63;
    if (which == 2) {
#pragma unroll
      for (int n = 0; n < 4; ++n) {
        const int s = j0 + wc * 64 + n * 16 + col;
#pragma unroll
        for (int r = 0; r < 4; ++r)
          Vo[(size_t)(h * DHEAD + d + r) * LSEQ + s] = f2bf(acc[m][n][r]);
      }
    } else {
      ushort_t* dst = which ? Ko : Qo;
      const float qs = which ? 1.0f : C2SCALE;  // fold softmax scale into Q
      const int t0 = d >> 1;
#pragma unroll
      for (int n = 0; n < 4; ++n) {
        const int s = j0 + wc * 64 + n * 16 + col;
        const float4 cst = *(const float4*)((const float*)rope + ((size_t)s << 6) + t0 * 2);
        ushort_t* ob = dst + ((size_t)h * LSEQ + s) * DHEAD;
        const float x1 = acc[m][n][0], x2 = acc[m][n][1];
        const float y1 = acc[m][n][2], y2 = acc[m][n][3];
        *(unsigned*)(ob + t0)      = bf16pair((x1 * cst.x - x2 * cst.y) * qs,
                                              (y1 * cst.z - y2 * cst.w) * qs);
        *(unsigned*)(ob + t0 + 32) = bf16pair((x1 * cst.y + x2 * cst.x) * qs,
                                              (y1 * cst.w + y2 * cst.z) * qs);
      }
    }
  }
}

// ---------------------------------------------------------------------------
// m97-style bf16 MFMA GEMM + XOR-swizzled LDS. Now used for MODE 0 only
// (final projection): A=Om(bf16), B=Wo(bf16) -> fp32 C row-major.
// ---------------------------------------------------------------------------
template<int MODE>
__global__ __launch_bounds__(256)
void mfma_gemm(const ushort_t* __restrict__ A, const ushort_t* __restrict__ B,
               float* __restrict__ C, const float2* __restrict__ rope,
               ushort_t* __restrict__ Qo, ushort_t* __restrict__ Ko,
               ushort_t* __restrict__ Vo) {
  __shared__ ushort_t As[128 * 64];
  __shared__ ushort_t Bs[128 * 64];
  const int tid  = threadIdx.x;
  const int w    = tid >> 6, lane = tid & 63;
  const int wm   = w >> 1,   wn   = w & 1;
  const int quad = lane >> 4, col = lane & 15;
  const int csw  = col & 7;   // row-derived swizzle key: read row % 8 == col % 8
  const int i0 = blockIdx.x * 128;
  const int j0 = blockIdx.y * 128;

  const ushort_t* Ab = A + (size_t)i0 * DMODEL;
  const ushort_t* Bb = B + (size_t)j0 * DMODEL;

  floatx4 acc[4][4];
#pragma unroll
  for (int mt = 0; mt < 4; ++mt)
#pragma unroll
    for (int nt = 0; nt < 4; ++nt) acc[mt][nt] = (floatx4){0.f, 0.f, 0.f, 0.f};

  const int lrow = lane >> 3;
  const int lcol = ((lane & 7) ^ lrow) * 8;

  for (int k0 = 0; k0 < DMODEL; k0 += 64) {
    __syncthreads();
#pragma unroll
    for (int it = 0; it < 4; ++it) {
      const int rb = (it * 4 + w) * 8;
      gl_lds16(Ab + (size_t)(rb + lrow) * DMODEL + k0 + lcol, As + rb * 64);
      gl_lds16(Bb + (size_t)(rb + lrow) * DMODEL + k0 + lcol, Bs + rb * 64);
    }
    __syncthreads();

#pragma unroll
    for (int kk = 0; kk < 64; kk += 32) {
      const int cblk = (kk >> 3) + quad;
      bf16x8 af[4], bfr[4];
#pragma unroll
      for (int mt = 0; mt < 4; ++mt)
        af[mt] = *(const bf16x8*)(As + (wm * 64 + mt * 16 + col) * 64 +
                                  ((cblk ^ csw) * 8));
#pragma unroll
      for (int nt = 0; nt < 4; ++nt)
        bfr[nt] = *(const bf16x8*)(Bs + (wn * 64 + nt * 16 + col) * 64 +
                                   ((cblk ^ csw) * 8));
#pragma unroll
      for (int mt = 0; mt < 4; ++mt)
#pragma unroll
        for (int nt = 0; nt < 4; ++nt)
          acc[mt][nt] = __builtin_amdgcn_mfma_f32_16x16x32_bf16(
              af[mt], bfr[nt], acc[mt][nt], 0, 0, 0);
    }
  }

  if (MODE == 0) {
#pragma unroll
    for (int mt = 0; mt < 4; ++mt) {
      const int i = i0 + wm * 64 + mt * 16 + quad * 4;
#pragma unroll
      for (int nt = 0; nt < 4; ++nt) {
        const int j = j0 + wn * 64 + nt * 16 + col;
#pragma unroll
        for (int r = 0; r < 4; ++r)
          C[(size_t)(i + r) * DMODEL + j] = acc[mt][nt][r];
      }
    }
  } else {
    const int which = i0 >> 10;               // 0=Q 1=K 2=V
#pragma unroll
    for (int mt = 0; mt < 4; ++mt) {
      const int f0 = i0 + wm * 64 + mt * 16 + quad * 4;
      const int h  = (f0 >> 6) & 15;
      const int d  = f0 & 63;
      if (which == 2) {
#pragma unroll
        for (int nt = 0; nt < 4; ++nt) {
          const int s = j0 + wn * 64 + nt * 16 + col;
#pragma unroll
          for (int r = 0; r < 4; ++r)
            Vo[(size_t)(h * DHEAD + d + r) * LSEQ + s] = f2bf(acc[mt][nt][r]);
        }
      } else {
        ushort_t* dst = which ? Ko : Qo;
        const float qs = which ? 1.0f : C2SCALE;
        const int t0 = d >> 1;
#pragma unroll
        for (int nt = 0; nt < 4; ++nt) {
          const int s = j0 + wn * 64 + nt * 16 + col;
          const float4 cst = *(const float4*)((const float*)rope + ((size_t)s << 6) + t0 * 2);
          ushort_t* ob = dst + ((size_t)h * LSEQ + s) * DHEAD;
          const float x1 = acc[mt][nt][0], x2 = acc[mt][nt][1];
          const float y1 = acc[mt][nt][2], y2 = acc[mt][nt][3];
          *(unsigned*)(ob + t0)      = bf16pair((x1 * cst.x - x2 * cst.y) * qs,
                                                (y1 * cst.z - y2 * cst.w) * qs);
          *(unsigned*)(ob + t0 + 32) = bf16pair((x1 * cst.y + x2 * cst.x) * qs,
                                                (y1 * cst.w + y2 * cst.z) * qs);
        }
      }
    }
  }
}

// ---------------------------------------------------------------------------
// MFMA flash attention v11 = kt-parity wave-group split (unchanged).
// 1024-thread blocks, 16 waves = 4 q-units x 2 key-halves x 2 KT-PARITY
// groups. Group ktpar processes tiles kt = 2*ktt+ktpar with its own LDS
// double-buffer (4 tile buffers total). Epilogue merges 4 partials.
// ---------------------------------------------------------------------------
__global__ __launch_bounds__(1024, 4)
void attn_mfma(const ushort_t* __restrict__ Qh, const ushort_t* __restrict__ Kh,
               const ushort_t* __restrict__ Vt, ushort_t* __restrict__ Om) {
  const int h   = blockIdx.x;
  const int g   = blockIdx.y;    // 0..15
  const int tid = threadIdx.x;
  const int w     = tid >> 6;      // 0..15
  const int wl    = w & 3;         // q-unit slot (32 q rows each)
  const int half  = (w >> 2) & 1;  // keys [0,32) or [32,64) of each tile
  const int ktpar = w >> 3;        // 0 = even tiles, 1 = odd tiles
  const int wg    = w & 7;         // staging wave index within parity group
  const int lane = tid & 63;
  const int quad = lane >> 4;
  const int col  = lane & 15;
  const int csw  = col & 7;      // row-derived swizzle key for reads

  __shared__ __align__(16) char smem[106496];
  ushort_t* Ks   = (ushort_t*)smem;                  // [4][64*64], swizzled
  ushort_t* Vs   = (ushort_t*)(smem + 32768);        // [4][64*64], swizzled
  ushort_t* Ps   = (ushort_t*)(smem + 65536);        // [16][32*PSTRIDE]
  float*    Obuf = (float*)smem;
  __shared__ float lbuf[3][4][2][16];
  ushort_t* psw = Ps + w * (32 * PSTRIDE);

  const int srow = wg * 8 + (lane >> 3);
  const int scol = (((lane & 7) ^ ((lane >> 3) & 7)) * 8);

  for (int pass = 0; pass < 2; ++pass) {
    const int qb      = pass ? (31 - g) : g;
    const int qbase   = qb * 128 + wl * 32;
    const int nkt_max = 2 * qb + 2;   // uniform across all waves, always even
    const int nt2     = nkt_max >> 1; // tiles per parity group

    bf16x8 qf[2][2];
#pragma unroll
    for (int nq = 0; nq < 2; ++nq)
#pragma unroll
      for (int c = 0; c < 2; ++c)
        qf[nq][c] = *(const bf16x8*)(Qh +
            ((size_t)(h * LSEQ + qbase + nq * 16 + col)) * DHEAD + quad * 8 + c * 32);

    floatx4 ot[4][2];
#pragma unroll
    for (int md = 0; md < 4; ++md)
#pragma unroll
      for (int nq = 0; nq < 2; ++nq) ot[md][nq] = (floatx4){0.f, 0.f, 0.f, 0.f};
    float l_[2] = {0.f, 0.f};

    auto stage = [&](int kt, int b) {
      const int key0 = kt * 64;
      const int boff = (ktpar * 2 + b) * 4096;
      gl_lds16(Kh + ((size_t)(h * LSEQ + key0 + srow)) * DHEAD + scol,
               Ks + boff + wg * 512);
      gl_lds16(Vt + ((size_t)(h * DHEAD + srow)) * LSEQ + key0 + scol,
               Vs + boff + wg * 512);
    };

    stage(ktpar, 0);   // group 0 stages tile 0, group 1 stages tile 1
    __syncthreads();   // staging visible (barrier drains vmcnt)

    for (int ktt = 0; ktt < nt2; ++ktt) {
      const int kt  = 2 * ktt + ktpar;
      const int buf = ktt & 1;
      if (ktt + 1 < nt2) stage(kt + 2, buf ^ 1);  // fills group's other buffer

      const ushort_t* kb = Ks + (ktpar * 2 + buf) * 4096;
      const ushort_t* vb = Vs + (ktpar * 2 + buf) * 4096;

      bf16x8 kf[2][2];
#pragma unroll
      for (int mk = 0; mk < 2; ++mk)
#pragma unroll
        for (int c = 0; c < 2; ++c)
          kf[mk][c] = *(const bf16x8*)(kb + (half * 32 + mk * 16 + col) * 64 +
                                       (((c * 4 + quad) ^ csw) * 8));

      floatx4 st[2][2];
#pragma unroll
      for (int mk = 0; mk < 2; ++mk)
#pragma unroll
        for (int nq = 0; nq < 2; ++nq) st[mk][nq] = (floatx4){0.f, 0.f, 0.f, 0.f};
#pragma unroll
      for (int mk = 0; mk < 2; ++mk)
#pragma unroll
        for (int c = 0; c < 2; ++c)
#pragma unroll
          for (int nq = 0; nq < 2; ++nq)
            st[mk][nq] = __builtin_amdgcn_mfma_f32_16x16x32_bf16(
                kf[mk][c], qf[nq][c], st[mk][nq], 0, 0, 0);

      if (kt >= nkt_max - 2) {
        const int key0 = kt * 64 + half * 32;
#pragma unroll
        for (int mk = 0; mk < 2; ++mk) {
          const int keyb = key0 + mk * 16 + quad * 4;
#pragma unroll
          for (int nq = 0; nq < 2; ++nq) {
            const int q = qbase + nq * 16 + col;
#pragma unroll
            for (int r = 0; r < 4; ++r)
              if (keyb + r > q) st[mk][nq][r] = MASKV;
          }
        }
      }

#pragma unroll
      for (int mk = 0; mk < 2; ++mk)
#pragma unroll
        for (int nq = 0; nq < 2; ++nq) {
#pragma unroll
          for (int r = 0; r < 4; ++r) st[mk][nq][r] = EXP2F(st[mk][nq][r]);
          l_[nq] += (st[mk][nq][0] + st[mk][nq][1]) + (st[mk][nq][2] + st[mk][nq][3]);
        }

#pragma unroll
      for (int mk = 0; mk < 2; ++mk)
#pragma unroll
        for (int nq = 0; nq < 2; ++nq) {
          uint2 pk;
          pk.x = bfpack_trunc(st[mk][nq][0], st[mk][nq][1]);
          pk.y = bfpack_trunc(st[mk][nq][2], st[mk][nq][3]);
          *(uint2*)(psw + (nq * 16 + col) * PSTRIDE + mk * 16 + quad * 4) = pk;
        }
      bf16x8 pf[2];
#pragma unroll
      for (int nq = 0; nq < 2; ++nq)
        pf[nq] = *(const bf16x8*)(psw + (nq * 16 + col) * PSTRIDE + quad * 8);

      bf16x8 vf[4];
#pragma unroll
      for (int md = 0; md < 4; ++md)
        vf[md] = *(const bf16x8*)(vb + (md * 16 + col) * 64 +
                                  (((half * 4 + quad) ^ csw) * 8));
#pragma unroll
      for (int md = 0; md < 4; ++md)
#pragma unroll
        for (int nq = 0; nq < 2; ++nq)
          ot[md][nq] = __builtin_amdgcn_mfma_f32_16x16x32_bf16(
              vf[md], pf[nq], ot[md][nq], 0, 0, 0);

      __syncthreads();  // staging kt+2 done; all reads of this buf finished
    }

    float lr[2];
#pragma unroll
    for (int nq = 0; nq < 2; ++nq) {
      float ls = l_[nq];
      ls += __shfl_xor(ls, 16);
      ls += __shfl_xor(ls, 32);
      lr[nq] = ls;
    }

    const int di = ((half << 1) | ktpar) - 1;  // -1 merger, else 0..2
    if (di >= 0) {
#pragma unroll
      for (int nq = 0; nq < 2; ++nq) {
        if (quad == 0) lbuf[di][wl][nq][col] = lr[nq];
#pragma unroll
        for (int md = 0; md < 4; ++md)
          *(float4*)(Obuf + di * 8704 + ((wl * 2 + nq) * 16 + col) * 68 + md * 16 + quad * 4) =
              (float4){ot[md][nq][0], ot[md][nq][1], ot[md][nq][2], ot[md][nq][3]};
      }
    }
    __syncthreads();

    if (di < 0) {  // merger group sums 4 partials and writes Om
#pragma unroll
      for (int nq = 0; nq < 2; ++nq) {
        const float inv = 1.0f / (lr[nq] + lbuf[0][wl][nq][col] +
                                  lbuf[1][wl][nq][col] + lbuf[2][wl][nq][col]);
        const int q = qbase + nq * 16 + col;
#pragma unroll
        for (int md = 0; md < 4; ++md) {
          const int ob_off = ((wl * 2 + nq) * 16 + col) * 68 + md * 16 + quad * 4;
          const float4 o0 = *(const float4*)(Obuf + ob_off);
          const float4 o1 = *(const float4*)(Obuf + 8704 + ob_off);
          const float4 o2 = *(const float4*)(Obuf + 17408 + ob_off);
          uint2 pk;
          pk.x = bf16pair((ot[md][nq][0] + o0.x + o1.x + o2.x) * inv,
                          (ot[md][nq][1] + o0.y + o1.y + o2.y) * inv);
          pk.y = bf16pair((ot[md][nq][2] + o0.z + o1.z + o2.z) * inv,
                          (ot[md][nq][3] + o0.w + o1.w + o2.w) * inv);
          *(uint2*)(Om + (size_t)q * DMODEL + h * DHEAD + md * 16 + quad * 4) = pk;
        }
      }
    }
    __syncthreads();  // Obuf reads done before next pass re-stages over it
  }
}

extern "C" void kernel_launch(void* const* d_in, const int* in_sizes, int n_in,
                              void* d_out, int out_size, void* d_ws, size_t ws_size,
                              hipStream_t stream) {
  const float* x  = (const float*)d_in[0];
  const float* Wq = (const float*)d_in[2];
  const float* Wk = (const float*)d_in[3];
  const float* Wv = (const float*)d_in[4];
  const float* Wo = (const float*)d_in[5];
  float* out = (float*)d_out;

  const size_t M1 = (size_t)1 << 20;
  ushort_t* xb  = (ushort_t*)d_ws;      // bf16 x          4M elems
  ushort_t* Wb  = xb  + 4 * M1;         // bf16 Wq|Wk|Wv   3M (contiguous)
  ushort_t* wob = Wb  + 3 * M1;         // bf16 Wo         1M
  ushort_t* Qh  = wob + 1 * M1;         // bf16 [H][L][DH] 4M (pre-scaled C2)
  ushort_t* Kh  = Qh  + 4 * M1;         // bf16 [H][L][DH] 4M
  ushort_t* Vt  = Kh  + 4 * M1;         // bf16 [H][DH][L] 4M
  ushort_t* Om  = Vt  + 4 * M1;         // bf16 [L][D]     4M
  float2*   rope = (float2*)(Om + 4 * M1);  // 4096x32 float2, 1 MB

  rope_table<<<512, 256, 0, stream>>>(rope);
  cvt_bf16<<<8192, 256, 0, stream>>>(x, Wq, Wk, Wv, Wo, xb);
  gemm256_qkv<<<dim3(3072 / 256, LSEQ / 256), 512, 0, stream>>>(
      Wb, xb, rope, Qh, Kh, Vt);
  attn_mfma<<<dim3(NH, 16), 1024, 0, stream>>>(Qh, Kh, Vt, Om);
  mfma_gemm<0><<<dim3(LSEQ / 128, DMODEL / 128), 256, 0, stream>>>(
      Om, wob, out, nullptr, nullptr, nullptr, nullptr);
}